// Round 13
// baseline (101.999 us; speedup 1.0000x reference)
//
#include <hip/hip_runtime.h>
#include <hip/hip_bf16.h>

typedef unsigned int uint;
typedef unsigned short ushort;

// Dims
#define Bn 16
#define Dd 256
#define Nn 4096
#define Hh 4
#define Kk 16
#define Vv 64
#define Rr 23
#define Cc 144   // 64 q + 16 k + 64 v
#define NRT 9    // 144/16 row-tiles

typedef short bf16x8s __attribute__((ext_vector_type(8)));
typedef float f32x4 __attribute__((ext_vector_type(4)));

static __device__ __forceinline__ ushort f2bf(float f) {
    __hip_bfloat16 h = __float2bfloat16(f);
    return __builtin_bit_cast(ushort, h);
}
static __device__ __forceinline__ float bf2f(ushort u) {
    return __uint_as_float(((uint)u) << 16);
}
static __device__ __forceinline__ float bflo(uint u) { return __uint_as_float(u << 16); }
static __device__ __forceinline__ float bfhi(uint u) { return __uint_as_float(u & 0xffff0000u); }

// ---------------- Kernel 1: pack 144 BN-folded rows (bf16, A-fragment order) ----------------
__global__ __launch_bounds__(256) void pack_kernel(
    const float* __restrict__ Wq, const float* __restrict__ qg, const float* __restrict__ qb,
    const float* __restrict__ qm, const float* __restrict__ qv,
    const float* __restrict__ Wk, const float* __restrict__ Wv,
    const float* __restrict__ vg, const float* __restrict__ vb,
    const float* __restrict__ vm, const float* __restrict__ vvar,
    ushort* __restrict__ Wf16, float* __restrict__ bias) {
    int c = blockIdx.x;       // 0..143
    int d = threadIdx.x;      // 0..255
    float scale, bs;
    const float* src;
    if (c < 64) {
        scale = qg[c] * rsqrtf(qv[c] + 1e-5f);
        bs = qb[c] - qm[c] * scale;
        src = Wq + c * Dd;
    } else if (c < 80) {
        scale = 1.f; bs = 0.f;
        src = Wk + (c - 64) * Dd;
    } else {
        int j = c - 80;
        scale = vg[j] * rsqrtf(vvar[j] + 1e-5f);
        bs = vb[j] - vm[j] * scale;
        src = Wv + j * Dd;
    }
    int rt = c >> 4, lm = c & 15;
    int kk = d >> 5, hi = (d >> 3) & 3, j = d & 7;
    Wf16[((rt * 8 + kk) * 64 + hi * 16 + lm) * 8 + j] = f2bf(src[d] * scale);
    if (d == 0) bias[c] = bs;
}

// ---------------- Kernel 2: MFMA projection -> consumer-layout buffers ----------------
// 4 phases x 2 ksteps: Wlds = 18.4 KB -> 8 blocks/CU (32 waves/CU) so TLP hides the
// per-kstep x-load latency (8 waves/SIMD x ~80cy work ~ 600cy latency). VGPR 64.
__global__ __launch_bounds__(256, 8) void proj_mfma_kernel(
    const float* __restrict__ x, const ushort* __restrict__ Wf16,
    const float* __restrict__ bias,
    ushort* __restrict__ qbufT, float* __restrict__ kbuf,
    ushort* __restrict__ vbufT) {
    __shared__ ushort Wlds[NRT * 2 * 64 * 8];   // 18432 B (2 k-steps per phase)

    int b = blockIdx.y;
    int n0 = blockIdx.x * 64;
    int t = threadIdx.x;
    int w = t >> 6, l = t & 63;
    int lm = l & 15, hi = l >> 4;
    int n = n0 + w * 16 + lm;     // this lane's output column

    const uint* WfU = (const uint*)Wf16;
    uint* WldsU = (uint*)Wlds;

    f32x4 acc[NRT];
#pragma unroll
    for (int rt = 0; rt < NRT; rt++) acc[rt] = (f32x4){0.f, 0.f, 0.f, 0.f};

    const float* xb = x + (size_t)b * Dd * Nn + n;

#pragma unroll
    for (int p = 0; p < 4; p++) {
        int kb = p * 2;
        if (p) __syncthreads();
        // stage W for 2 ksteps: 4608 dwords = 18 iters
#pragma unroll
        for (int i = 0; i < 18; i++) {
            int flat = t + 256 * i;
            int f2 = flat >> 8;          // rt*2 + kkl
            int rt = f2 >> 1, kkl = f2 & 1;
            WldsU[flat] = WfU[((rt * 8 + kb + kkl) << 8) + (flat & 255)];
        }
        __syncthreads();

#pragma unroll
        for (int kkl = 0; kkl < 2; kkl++) {
            int kk = kb + kkl;
            const float* xp = xb + (size_t)(kk * 32 + hi * 8) * Nn;
            float f[8];
#pragma unroll
            for (int j = 0; j < 8; j++) f[j] = xp[(size_t)j * Nn];
            bf16x8s bfrag;
#pragma unroll
            for (int j = 0; j < 8; j++) bfrag[j] = (short)f2bf(f[j]);
#pragma unroll
            for (int rt = 0; rt < NRT; rt++) {
                bf16x8s afrag = *reinterpret_cast<const bf16x8s*>(
                    &Wlds[(size_t)((rt * 2 + kkl) * 64 + l) * 8]);
                acc[rt] = __builtin_amdgcn_mfma_f32_16x16x32_bf16(afrag, bfrag, acc[rt], 0, 0, 0);
            }
        }
    }

    // ---- epilogue ----
    // kbuf (rows 64..79 = rt 4): channel-major, already coalesced -> direct store
#pragma unroll
    for (int rr = 0; rr < 4; rr++) {
        int kc = hi * 4 + rr;
        kbuf[((size_t)b * 16 + kc) * Nn + n] = acc[4][rr] + bias[64 + kc];
    }

    __syncthreads();   // done reading Wlds; reuse as transpose buffer (exactly 18432 B)
    // layout (ushort offsets): q = nl*72 + k*4 + h  (64 rows x 72 = 4608)
    //                          v = 4608 + nl*72 + v (64 rows x 72 = 4608)
    {
        int nl = w * 16 + lm;
#pragma unroll
        for (int rt = 0; rt < 4; rt++)
#pragma unroll
            for (int rr = 0; rr < 4; rr++) {
                int kq = hi * 4 + rr;
                Wlds[nl * 72 + kq * 4 + rt] = f2bf(acc[rt][rr] + bias[rt * 16 + kq]);
            }
#pragma unroll
        for (int rt = 5; rt < 9; rt++)
#pragma unroll
            for (int rr = 0; rr < 4; rr++) {
                int v = (rt - 5) * 16 + hi * 4 + rr;
                Wlds[4608 + nl * 72 + v] = f2bf(acc[rt][rr] + bias[80 + v]);
            }
    }
    __syncthreads();

    // ---- coalesced stores from LDS ----
#pragma unroll
    for (int m = 0; m < 2; m++) {
        int i = t + 256 * m;
        int row = i >> 3, seg = i & 7;
        uint4 u = *reinterpret_cast<const uint4*>(&Wlds[row * 72 + seg * 8]);
        *reinterpret_cast<uint4*>(&qbufT[((size_t)b * Nn + n0 + row) * 64 + seg * 8]) = u;
    }
#pragma unroll
    for (int m = 0; m < 2; m++) {
        int i = t + 256 * m;
        int row = i >> 3, seg = i & 7;
        uint4 u = *reinterpret_cast<const uint4*>(&Wlds[4608 + row * 72 + seg * 8]);
        *reinterpret_cast<uint4*>(&vbufT[((size_t)b * Nn + n0 + row) * 64 + seg * 8]) = u;
    }
}

// ---------------- Kernel 2b: g_kernel — gbuf[b][r][n][h] = sum_k q[k][h] * cw[k][r] ---------
__global__ __launch_bounds__(256) void g_kernel(
    const ushort* __restrict__ qbufT, const float* __restrict__ conv_w,
    ushort* __restrict__ gbuf) {
    __shared__ float cws[Kk][24];   // [k][r], padded
    int b = blockIdx.y;
    int n = blockIdx.x * 256 + threadIdx.x;
    int t = threadIdx.x;
    for (int i = t; i < Kk * Rr; i += 256) cws[i / Rr][i % Rr] = conv_w[i];
    __syncthreads();

    float qf[16][4];
    const uint4* qp = reinterpret_cast<const uint4*>(&qbufT[((size_t)b * Nn + n) * 64]);
#pragma unroll
    for (int m = 0; m < 8; m++) {
        uint4 u = qp[m];
        uint vals[4] = {u.x, u.y, u.z, u.w};
#pragma unroll
        for (int j = 0; j < 4; j++) {
            int idx = m * 8 + j * 2;        // = k*4 + h, h even
            int k = idx >> 2, h = idx & 3;
            qf[k][h]     = bflo(vals[j]);
            qf[k][h + 1] = bfhi(vals[j]);
        }
    }

#pragma unroll
    for (int r = 0; r < Rr; r++) {
        float g0 = 0.f, g1 = 0.f, g2 = 0.f, g3 = 0.f;
#pragma unroll
        for (int k = 0; k < 16; k++) {
            float c = cws[k][r];
            g0 += qf[k][0] * c;
            g1 += qf[k][1] * c;
            g2 += qf[k][2] * c;
            g3 += qf[k][3] * c;
        }
        uint2 o;
        o.x = ((uint)f2bf(g1) << 16) | (uint)f2bf(g0);
        o.y = ((uint)f2bf(g3) << 16) | (uint)f2bf(g2);
        *reinterpret_cast<uint2*>(&gbuf[(((size_t)b * Rr + r) * Nn + n) * 4]) = o;
    }
}

// ---------------- Kernel 3: softmax over n for k channels (kbuf) ----------------
__global__ __launch_bounds__(256) void softmax_kernel(float* __restrict__ kbuf) {
    int b = blockIdx.y, kc = blockIdx.x;
    float* row = kbuf + ((size_t)b * 16 + kc) * Nn;
    int t = threadIdx.x;
    float vals[16];
    float m = -1e30f;
#pragma unroll
    for (int i = 0; i < 16; i++) {
        vals[i] = row[t + 256 * i];
        m = fmaxf(m, vals[i]);
    }
#pragma unroll
    for (int off = 32; off; off >>= 1) m = fmaxf(m, __shfl_xor(m, off));
    __shared__ float sm[4], ss[4];
    int wave = t >> 6;
    if ((t & 63) == 0) sm[wave] = m;
    __syncthreads();
    m = fmaxf(fmaxf(sm[0], sm[1]), fmaxf(sm[2], sm[3]));
    float s = 0.f;
#pragma unroll
    for (int i = 0; i < 16; i++) {
        vals[i] = __expf(vals[i] - m);
        s += vals[i];
    }
#pragma unroll
    for (int off = 32; off; off >>= 1) s += __shfl_xor(s, off);
    if ((t & 63) == 0) ss[wave] = s;
    __syncthreads();
    s = ss[0] + ss[1] + ss[2] + ss[3];
    float inv = 1.f / s;
#pragma unroll
    for (int i = 0; i < 16; i++) row[t + 256 * i] = vals[i] * inv;
}

// ---------------- Kernel 4: lam_c[b][16][64] = sum_n kk*vv ----------------
#define NCHUNK 128
__global__ __launch_bounds__(256) void lamc_kernel(
    const float* __restrict__ kbuf, const ushort* __restrict__ vbufT,
    float* __restrict__ lam) {
    int b = blockIdx.y;
    int n0 = blockIdx.x * NCHUNK;
    __shared__ float kks[Kk][NCHUNK + 1];   // 8256 B
    __shared__ ushort vvT[NCHUNK][72];      // 18432 B, rows 144 B
    int t = threadIdx.x;
#pragma unroll
    for (int m = 0; m < 2; m++) {
        int i = t + 256 * m;
        int r = i >> 5, seg = i & 31;
        float4 f = *reinterpret_cast<const float4*>(&kbuf[((size_t)b * 16 + r) * Nn + n0 + seg * 4]);
        kks[r][seg * 4 + 0] = f.x;
        kks[r][seg * 4 + 1] = f.y;
        kks[r][seg * 4 + 2] = f.z;
        kks[r][seg * 4 + 3] = f.w;
    }
#pragma unroll
    for (int m = 0; m < 4; m++) {
        int i = t + 256 * m;
        int row = i >> 3, seg = i & 7;
        uint4 u = *reinterpret_cast<const uint4*>(&vbufT[((size_t)b * Nn + n0 + row) * 64 + seg * 8]);
        *reinterpret_cast<uint4*>(&vvT[row][seg * 8]) = u;
    }
    __syncthreads();
    int v = t & 63, k0 = t >> 6;
    float acc4[4] = {0.f, 0.f, 0.f, 0.f};
    for (int nl = 0; nl < NCHUNK; nl++) {
        float wv = bf2f(vvT[nl][v]);
#pragma unroll
        for (int j2 = 0; j2 < 4; j2++) acc4[j2] += kks[k0 + 4 * j2][nl] * wv;
    }
#pragma unroll
    for (int j2 = 0; j2 < 4; j2++)
        atomicAdd(&lam[((size_t)b * Kk + k0 + 4 * j2) * Vv + v], acc4[j2]);
}

// ---------------- Kernel 5: fused position-lambda + apply (R11 version) ----------------
#define TN 32
__global__ __launch_bounds__(256, 6) void fused_out_kernel(
    const ushort* __restrict__ qbufT, const ushort* __restrict__ vbufT,
    const ushort* __restrict__ gbuf, const float* __restrict__ lam,
    const float* __restrict__ conv_b, float* __restrict__ out) {
    __shared__ ushort vvsT[54][72];       // [j][v] bf16; n = n0-11+j; rows 144 B
    __shared__ ushort qsT[TN][68];        // [np][k*4+h] bf16; rows 136 B
    __shared__ ushort gsT[Rr][TN][4];     // [r][np][h] bf16 (linear copy of gbuf chunk)
    __shared__ float  lcs[Kk][Vv];        // lam_c + conv_b

    int b = blockIdx.y;
    int n0 = blockIdx.x * TN;
    int t = threadIdx.x;

    // ---- load phase (all globals issued before any LDS write) ----
    uint4 gld0, gld1;
    {
        int i = t;
        int r = i >> 4, seg = i & 15;
        if (i < 368)
            gld0 = *reinterpret_cast<const uint4*>(&gbuf[(((size_t)b * Rr + r) * Nn + n0) * 4 + seg * 8]);
        int i2 = t + 256;
        int r2 = i2 >> 4, seg2 = i2 & 15;
        if (i2 < 368)
            gld1 = *reinterpret_cast<const uint4*>(&gbuf[(((size_t)b * Rr + r2) * Nn + n0) * 4 + seg2 * 8]);
    }
    uint2 qld0, qld1;
    {
        int i = t;
        int np = i >> 4, seg = i & 15;
        qld0 = *reinterpret_cast<const uint2*>(&qbufT[((size_t)b * Nn + n0 + np) * 64 + seg * 4]);
        int i2 = t + 256;
        int np2 = i2 >> 4, seg2 = i2 & 15;
        qld1 = *reinterpret_cast<const uint2*>(&qbufT[((size_t)b * Nn + n0 + np2) * 64 + seg2 * 4]);
    }
    uint4 vld0 = {0, 0, 0, 0}, vld1 = {0, 0, 0, 0};
    {
        int i = t;
        int j = i >> 3, seg = i & 7;
        int nn = n0 - 11 + j;
        if (nn >= 0 && nn < Nn)
            vld0 = *reinterpret_cast<const uint4*>(&vbufT[((size_t)b * Nn + nn) * 64 + seg * 8]);
        int i2 = t + 256;
        int j2 = i2 >> 3, seg2 = i2 & 7;
        int nn2 = n0 - 11 + j2;
        if (i2 < 432 && nn2 >= 0 && nn2 < Nn)
            vld1 = *reinterpret_cast<const uint4*>(&vbufT[((size_t)b * Nn + nn2) * 64 + seg2 * 8]);
    }
    float lld[4];
#pragma unroll
    for (int m = 0; m < 4; m++) {
        int i = t + 256 * m;
        lld[m] = lam[(size_t)b * Kk * Vv + i] + conv_b[i >> 6];
    }

    // ---- write phase ----
    {
        int i = t;
        if (i < 368) *(reinterpret_cast<uint4*>(gsT) + i) = gld0;
        int i2 = t + 256;
        if (i2 < 368) *(reinterpret_cast<uint4*>(gsT) + i2) = gld1;
    }
    {
        int i = t;
        int np = i >> 4, seg = i & 15;
        *reinterpret_cast<uint2*>(&qsT[np][seg * 4]) = qld0;
        int i2 = t + 256;
        int np2 = i2 >> 4, seg2 = i2 & 15;
        *reinterpret_cast<uint2*>(&qsT[np2][seg2 * 4]) = qld1;
    }
    {
        int i = t;
        int j = i >> 3, seg = i & 7;
        *reinterpret_cast<uint4*>(&vvsT[j][seg * 8]) = vld0;
        int i2 = t + 256;
        if (i2 < 432) {
            int j2 = i2 >> 3, seg2 = i2 & 7;
            *reinterpret_cast<uint4*>(&vvsT[j2][seg2 * 8]) = vld1;
        }
    }
#pragma unroll
    for (int m = 0; m < 4; m++) {
        int i = t + 256 * m;
        lcs[i >> 6][i & 63] = lld[m];
    }
    __syncthreads();

    // ---- main ----
    int np = t & 31;
    int vgp = t >> 5;

    float acc[4][8];
#pragma unroll
    for (int h = 0; h < 4; h++)
#pragma unroll
        for (int vl = 0; vl < 8; vl++) acc[h][vl] = 0.f;

#pragma unroll
    for (int r = 0; r < Rr; r++) {
        ushort4 g4 = *reinterpret_cast<const ushort4*>(&gsT[r][np][0]);
        uint4 w4 = *reinterpret_cast<const uint4*>(&vvsT[np + r][vgp * 8]);
        float gh[4] = {bf2f(g4.x), bf2f(g4.y), bf2f(g4.z), bf2f(g4.w)};
        float wv[8];
        wv[0] = bflo(w4.x); wv[1] = bfhi(w4.x);
        wv[2] = bflo(w4.y); wv[3] = bfhi(w4.y);
        wv[4] = bflo(w4.z); wv[5] = bfhi(w4.z);
        wv[6] = bflo(w4.w); wv[7] = bfhi(w4.w);
#pragma unroll
        for (int h = 0; h < 4; h++)
#pragma unroll
            for (int vl = 0; vl < 8; vl++) acc[h][vl] += gh[h] * wv[vl];
    }

#pragma unroll
    for (int k = 0; k < 16; k++) {
        ushort4 q4 = *reinterpret_cast<const ushort4*>(&qsT[np][k * 4]);
        float qh[4] = {bf2f(q4.x), bf2f(q4.y), bf2f(q4.z), bf2f(q4.w)};
        const float4* lr = reinterpret_cast<const float4*>(&lcs[k][vgp * 8]);
        float4 la = lr[0], lb = lr[1];
        float lv[8] = {la.x, la.y, la.z, la.w, lb.x, lb.y, lb.z, lb.w};
#pragma unroll
        for (int h = 0; h < 4; h++)
#pragma unroll
            for (int vl = 0; vl < 8; vl++) acc[h][vl] += qh[h] * lv[vl];
    }

    float* ob = out + (size_t)b * 256 * Nn + n0 + np;
#pragma unroll
    for (int h = 0; h < 4; h++)
#pragma unroll
        for (int vl = 0; vl < 8; vl++)
            ob[(size_t)(h * 64 + vgp * 8 + vl) * Nn] = acc[h][vl];
}

extern "C" void kernel_launch(void* const* d_in, const int* in_sizes, int n_in,
                              void* d_out, int out_size, void* d_ws, size_t ws_size,
                              hipStream_t stream) {
    const float* x      = (const float*)d_in[0];
    const float* Wq     = (const float*)d_in[1];
    const float* qg     = (const float*)d_in[2];
    const float* qb     = (const float*)d_in[3];
    const float* qm     = (const float*)d_in[4];
    const float* qv     = (const float*)d_in[5];
    const float* Wk     = (const float*)d_in[6];
    const float* Wv     = (const float*)d_in[7];
    const float* vg     = (const float*)d_in[8];
    const float* vb     = (const float*)d_in[9];
    const float* vm     = (const float*)d_in[10];
    const float* vvar   = (const float*)d_in[11];
    const float* conv_w = (const float*)d_in[12];
    const float* conv_b = (const float*)d_in[13];
    float* out = (float*)d_out;

    float* wsf = (float*)d_ws;
    ushort* Wf16  = (ushort*)wsf;                       // 36864 u16 = 18432 f
    float*  bias  = wsf + 18432;                        // 256 f
    float*  kbuf  = wsf + 18688;                        // 16*16*4096 = 1048576 f
    float*  lam   = wsf + 1067264;                      // 16384 f
    ushort* qbufT = (ushort*)(wsf + 1083648);           // 16*4096*64 u16 = 2097152 f
    ushort* vbufT = (ushort*)(wsf + 3180800);           // 16*4096*64 u16 = 2097152 f
    ushort* gbuf  = (ushort*)(wsf + 5277952);           // 16*23*4096*4 u16 = 3014656 f

    pack_kernel<<<Cc, 256, 0, stream>>>(Wq, qg, qb, qm, qv, Wk, Wv, vg, vb, vm, vvar,
                                        Wf16, bias);
    proj_mfma_kernel<<<dim3(Nn / 64, Bn), 256, 0, stream>>>(x, Wf16, bias,
                                                            qbufT, kbuf, vbufT);
    g_kernel<<<dim3(Nn / 256, Bn), 256, 0, stream>>>(qbufT, conv_w, gbuf);
    softmax_kernel<<<dim3(Kk, Bn), 256, 0, stream>>>(kbuf);
    hipMemsetAsync(lam, 0, (size_t)Bn * Kk * Vv * sizeof(float), stream);
    lamc_kernel<<<dim3(Nn / NCHUNK, Bn), 256, 0, stream>>>(kbuf, vbufT, lam);
    fused_out_kernel<<<dim3(Nn / TN, Bn), 256, 0, stream>>>(qbufT, vbufT, gbuf, lam,
                                                            conv_b, out);
}

// Round 14
// 75.043 us; speedup vs baseline: 1.3592x; 1.3592x over previous
//
#include <hip/hip_runtime.h>
#include <hip/hip_bf16.h>

typedef unsigned int uint;
typedef unsigned short ushort;

// Dims
#define Bn 16
#define Dd 256
#define Nn 4096
#define Hh 4
#define Kk 16
#define Vv 64
#define Rr 23
#define Cc 144   // 64 q + 16 k + 64 v
#define NRT 9    // 144/16 row-tiles

typedef short bf16x8s __attribute__((ext_vector_type(8)));
typedef float f32x4 __attribute__((ext_vector_type(4)));

static __device__ __forceinline__ ushort f2bf(float f) {
    __hip_bfloat16 h = __float2bfloat16(f);
    return __builtin_bit_cast(ushort, h);
}
static __device__ __forceinline__ float bf2f(ushort u) {
    return __uint_as_float(((uint)u) << 16);
}
static __device__ __forceinline__ float bflo(uint u) { return __uint_as_float(u << 16); }
static __device__ __forceinline__ float bfhi(uint u) { return __uint_as_float(u & 0xffff0000u); }

// ---------------- Kernel 1: pack 144 BN-folded rows (bf16, A-fragment order) ----------------
__global__ __launch_bounds__(256) void pack_kernel(
    const float* __restrict__ Wq, const float* __restrict__ qg, const float* __restrict__ qb,
    const float* __restrict__ qm, const float* __restrict__ qv,
    const float* __restrict__ Wk, const float* __restrict__ Wv,
    const float* __restrict__ vg, const float* __restrict__ vb,
    const float* __restrict__ vm, const float* __restrict__ vvar,
    ushort* __restrict__ Wf16, float* __restrict__ bias) {
    int c = blockIdx.x;       // 0..143
    int d = threadIdx.x;      // 0..255
    float scale, bs;
    const float* src;
    if (c < 64) {
        scale = qg[c] * rsqrtf(qv[c] + 1e-5f);
        bs = qb[c] - qm[c] * scale;
        src = Wq + c * Dd;
    } else if (c < 80) {
        scale = 1.f; bs = 0.f;
        src = Wk + (c - 64) * Dd;
    } else {
        int j = c - 80;
        scale = vg[j] * rsqrtf(vvar[j] + 1e-5f);
        bs = vb[j] - vm[j] * scale;
        src = Wv + j * Dd;
    }
    int rt = c >> 4, lm = c & 15;
    int kk = d >> 5, hi = (d >> 3) & 3, j = d & 7;
    Wf16[((rt * 8 + kk) * 64 + hi * 16 + lm) * 8 + j] = f2bf(src[d] * scale);
    if (d == 0) bias[c] = bs;
}

// ---------------- Kernel 2: MFMA projection -> consumer-layout buffers ----------------
// 4 phases x 2 ksteps: Wlds = 18.4 KB (8 blocks/CU by LDS). launch_bounds(256,4) keeps
// VGPR at its natural ~64 (no spill; R13's forced-8 bound spilled acc to scratch).
// With VGPR<=64 the HW can still schedule 8 waves/SIMD -> TLP hides x-load latency.
__global__ __launch_bounds__(256, 4) void proj_mfma_kernel(
    const float* __restrict__ x, const ushort* __restrict__ Wf16,
    const float* __restrict__ bias,
    ushort* __restrict__ qbufT, float* __restrict__ kbuf,
    ushort* __restrict__ vbufT) {
    __shared__ ushort Wlds[NRT * 2 * 64 * 8];   // 18432 B (2 k-steps per phase)

    int b = blockIdx.y;
    int n0 = blockIdx.x * 64;
    int t = threadIdx.x;
    int w = t >> 6, l = t & 63;
    int lm = l & 15, hi = l >> 4;
    int n = n0 + w * 16 + lm;     // this lane's output column

    const uint* WfU = (const uint*)Wf16;
    uint* WldsU = (uint*)Wlds;

    f32x4 acc[NRT];
#pragma unroll
    for (int rt = 0; rt < NRT; rt++) acc[rt] = (f32x4){0.f, 0.f, 0.f, 0.f};

    const float* xb = x + (size_t)b * Dd * Nn + n;

#pragma unroll
    for (int p = 0; p < 4; p++) {
        int kb = p * 2;
        if (p) __syncthreads();
        // stage W for 2 ksteps: 4608 dwords = 18 iters
#pragma unroll
        for (int i = 0; i < 18; i++) {
            int flat = t + 256 * i;
            int f2 = flat >> 8;          // rt*2 + kkl
            int rt = f2 >> 1, kkl = f2 & 1;
            WldsU[flat] = WfU[((rt * 8 + kb + kkl) << 8) + (flat & 255)];
        }
        __syncthreads();

#pragma unroll
        for (int kkl = 0; kkl < 2; kkl++) {
            int kk = kb + kkl;
            const float* xp = xb + (size_t)(kk * 32 + hi * 8) * Nn;
            float f[8];
#pragma unroll
            for (int j = 0; j < 8; j++) f[j] = xp[(size_t)j * Nn];
            bf16x8s bfrag;
#pragma unroll
            for (int j = 0; j < 8; j++) bfrag[j] = (short)f2bf(f[j]);
#pragma unroll
            for (int rt = 0; rt < NRT; rt++) {
                bf16x8s afrag = *reinterpret_cast<const bf16x8s*>(
                    &Wlds[(size_t)((rt * 2 + kkl) * 64 + l) * 8]);
                acc[rt] = __builtin_amdgcn_mfma_f32_16x16x32_bf16(afrag, bfrag, acc[rt], 0, 0, 0);
            }
        }
    }

    // ---- epilogue ----
    // kbuf (rows 64..79 = rt 4): channel-major, already coalesced -> direct store
#pragma unroll
    for (int rr = 0; rr < 4; rr++) {
        int kc = hi * 4 + rr;
        kbuf[((size_t)b * 16 + kc) * Nn + n] = acc[4][rr] + bias[64 + kc];
    }

    __syncthreads();   // done reading Wlds; reuse as transpose buffer (exactly 18432 B)
    // layout (ushort offsets): q = nl*72 + k*4 + h  (64 rows x 72 = 4608)
    //                          v = 4608 + nl*72 + v (64 rows x 72 = 4608)
    {
        int nl = w * 16 + lm;
#pragma unroll
        for (int rt = 0; rt < 4; rt++)
#pragma unroll
            for (int rr = 0; rr < 4; rr++) {
                int kq = hi * 4 + rr;
                Wlds[nl * 72 + kq * 4 + rt] = f2bf(acc[rt][rr] + bias[rt * 16 + kq]);
            }
#pragma unroll
        for (int rt = 5; rt < 9; rt++)
#pragma unroll
            for (int rr = 0; rr < 4; rr++) {
                int v = (rt - 5) * 16 + hi * 4 + rr;
                Wlds[4608 + nl * 72 + v] = f2bf(acc[rt][rr] + bias[80 + v]);
            }
    }
    __syncthreads();

    // ---- coalesced stores from LDS ----
#pragma unroll
    for (int m = 0; m < 2; m++) {
        int i = t + 256 * m;
        int row = i >> 3, seg = i & 7;
        uint4 u = *reinterpret_cast<const uint4*>(&Wlds[row * 72 + seg * 8]);
        *reinterpret_cast<uint4*>(&qbufT[((size_t)b * Nn + n0 + row) * 64 + seg * 8]) = u;
    }
#pragma unroll
    for (int m = 0; m < 2; m++) {
        int i = t + 256 * m;
        int row = i >> 3, seg = i & 7;
        uint4 u = *reinterpret_cast<const uint4*>(&Wlds[4608 + row * 72 + seg * 8]);
        *reinterpret_cast<uint4*>(&vbufT[((size_t)b * Nn + n0 + row) * 64 + seg * 8]) = u;
    }
}

// ---------------- Kernel 2b: g_kernel — gbuf[b][r][n][h] = sum_k q[k][h] * cw[k][r] ---------
__global__ __launch_bounds__(256) void g_kernel(
    const ushort* __restrict__ qbufT, const float* __restrict__ conv_w,
    ushort* __restrict__ gbuf) {
    __shared__ float cws[Kk][24];   // [k][r], padded
    int b = blockIdx.y;
    int n = blockIdx.x * 256 + threadIdx.x;
    int t = threadIdx.x;
    for (int i = t; i < Kk * Rr; i += 256) cws[i / Rr][i % Rr] = conv_w[i];
    __syncthreads();

    float qf[16][4];
    const uint4* qp = reinterpret_cast<const uint4*>(&qbufT[((size_t)b * Nn + n) * 64]);
#pragma unroll
    for (int m = 0; m < 8; m++) {
        uint4 u = qp[m];
        uint vals[4] = {u.x, u.y, u.z, u.w};
#pragma unroll
        for (int j = 0; j < 4; j++) {
            int idx = m * 8 + j * 2;        // = k*4 + h, h even
            int k = idx >> 2, h = idx & 3;
            qf[k][h]     = bflo(vals[j]);
            qf[k][h + 1] = bfhi(vals[j]);
        }
    }

#pragma unroll
    for (int r = 0; r < Rr; r++) {
        float g0 = 0.f, g1 = 0.f, g2 = 0.f, g3 = 0.f;
#pragma unroll
        for (int k = 0; k < 16; k++) {
            float c = cws[k][r];
            g0 += qf[k][0] * c;
            g1 += qf[k][1] * c;
            g2 += qf[k][2] * c;
            g3 += qf[k][3] * c;
        }
        uint2 o;
        o.x = ((uint)f2bf(g1) << 16) | (uint)f2bf(g0);
        o.y = ((uint)f2bf(g3) << 16) | (uint)f2bf(g2);
        *reinterpret_cast<uint2*>(&gbuf[(((size_t)b * Rr + r) * Nn + n) * 4]) = o;
    }
}

// ---------------- Kernel 3: softmax over n for k channels (kbuf) ----------------
__global__ __launch_bounds__(256) void softmax_kernel(float* __restrict__ kbuf) {
    int b = blockIdx.y, kc = blockIdx.x;
    float* row = kbuf + ((size_t)b * 16 + kc) * Nn;
    int t = threadIdx.x;
    float vals[16];
    float m = -1e30f;
#pragma unroll
    for (int i = 0; i < 16; i++) {
        vals[i] = row[t + 256 * i];
        m = fmaxf(m, vals[i]);
    }
#pragma unroll
    for (int off = 32; off; off >>= 1) m = fmaxf(m, __shfl_xor(m, off));
    __shared__ float sm[4], ss[4];
    int wave = t >> 6;
    if ((t & 63) == 0) sm[wave] = m;
    __syncthreads();
    m = fmaxf(fmaxf(sm[0], sm[1]), fmaxf(sm[2], sm[3]));
    float s = 0.f;
#pragma unroll
    for (int i = 0; i < 16; i++) {
        vals[i] = __expf(vals[i] - m);
        s += vals[i];
    }
#pragma unroll
    for (int off = 32; off; off >>= 1) s += __shfl_xor(s, off);
    if ((t & 63) == 0) ss[wave] = s;
    __syncthreads();
    s = ss[0] + ss[1] + ss[2] + ss[3];
    float inv = 1.f / s;
#pragma unroll
    for (int i = 0; i < 16; i++) row[t + 256 * i] = vals[i] * inv;
}

// ---------------- Kernel 4: lam_c[b][16][64] = sum_n kk*vv ----------------
#define NCHUNK 128
__global__ __launch_bounds__(256) void lamc_kernel(
    const float* __restrict__ kbuf, const ushort* __restrict__ vbufT,
    float* __restrict__ lam) {
    int b = blockIdx.y;
    int n0 = blockIdx.x * NCHUNK;
    __shared__ float kks[Kk][NCHUNK + 1];   // 8256 B
    __shared__ ushort vvT[NCHUNK][72];      // 18432 B, rows 144 B
    int t = threadIdx.x;
#pragma unroll
    for (int m = 0; m < 2; m++) {
        int i = t + 256 * m;
        int r = i >> 5, seg = i & 31;
        float4 f = *reinterpret_cast<const float4*>(&kbuf[((size_t)b * 16 + r) * Nn + n0 + seg * 4]);
        kks[r][seg * 4 + 0] = f.x;
        kks[r][seg * 4 + 1] = f.y;
        kks[r][seg * 4 + 2] = f.z;
        kks[r][seg * 4 + 3] = f.w;
    }
#pragma unroll
    for (int m = 0; m < 4; m++) {
        int i = t + 256 * m;
        int row = i >> 3, seg = i & 7;
        uint4 u = *reinterpret_cast<const uint4*>(&vbufT[((size_t)b * Nn + n0 + row) * 64 + seg * 8]);
        *reinterpret_cast<uint4*>(&vvT[row][seg * 8]) = u;
    }
    __syncthreads();
    int v = t & 63, k0 = t >> 6;
    float acc4[4] = {0.f, 0.f, 0.f, 0.f};
    for (int nl = 0; nl < NCHUNK; nl++) {
        float wv = bf2f(vvT[nl][v]);
#pragma unroll
        for (int j2 = 0; j2 < 4; j2++) acc4[j2] += kks[k0 + 4 * j2][nl] * wv;
    }
#pragma unroll
    for (int j2 = 0; j2 < 4; j2++)
        atomicAdd(&lam[((size_t)b * Kk + k0 + 4 * j2) * Vv + v], acc4[j2]);
}

// ---------------- Kernel 5: fused position-lambda + apply (R11 version) ----------------
#define TN 32
__global__ __launch_bounds__(256, 6) void fused_out_kernel(
    const ushort* __restrict__ qbufT, const ushort* __restrict__ vbufT,
    const ushort* __restrict__ gbuf, const float* __restrict__ lam,
    const float* __restrict__ conv_b, float* __restrict__ out) {
    __shared__ ushort vvsT[54][72];       // [j][v] bf16; n = n0-11+j; rows 144 B
    __shared__ ushort qsT[TN][68];        // [np][k*4+h] bf16; rows 136 B
    __shared__ ushort gsT[Rr][TN][4];     // [r][np][h] bf16 (linear copy of gbuf chunk)
    __shared__ float  lcs[Kk][Vv];        // lam_c + conv_b

    int b = blockIdx.y;
    int n0 = blockIdx.x * TN;
    int t = threadIdx.x;

    // ---- load phase (all globals issued before any LDS write) ----
    uint4 gld0, gld1;
    {
        int i = t;
        int r = i >> 4, seg = i & 15;
        if (i < 368)
            gld0 = *reinterpret_cast<const uint4*>(&gbuf[(((size_t)b * Rr + r) * Nn + n0) * 4 + seg * 8]);
        int i2 = t + 256;
        int r2 = i2 >> 4, seg2 = i2 & 15;
        if (i2 < 368)
            gld1 = *reinterpret_cast<const uint4*>(&gbuf[(((size_t)b * Rr + r2) * Nn + n0) * 4 + seg2 * 8]);
    }
    uint2 qld0, qld1;
    {
        int i = t;
        int np = i >> 4, seg = i & 15;
        qld0 = *reinterpret_cast<const uint2*>(&qbufT[((size_t)b * Nn + n0 + np) * 64 + seg * 4]);
        int i2 = t + 256;
        int np2 = i2 >> 4, seg2 = i2 & 15;
        qld1 = *reinterpret_cast<const uint2*>(&qbufT[((size_t)b * Nn + n0 + np2) * 64 + seg2 * 4]);
    }
    uint4 vld0 = {0, 0, 0, 0}, vld1 = {0, 0, 0, 0};
    {
        int i = t;
        int j = i >> 3, seg = i & 7;
        int nn = n0 - 11 + j;
        if (nn >= 0 && nn < Nn)
            vld0 = *reinterpret_cast<const uint4*>(&vbufT[((size_t)b * Nn + nn) * 64 + seg * 8]);
        int i2 = t + 256;
        int j2 = i2 >> 3, seg2 = i2 & 7;
        int nn2 = n0 - 11 + j2;
        if (i2 < 432 && nn2 >= 0 && nn2 < Nn)
            vld1 = *reinterpret_cast<const uint4*>(&vbufT[((size_t)b * Nn + nn2) * 64 + seg2 * 8]);
    }
    float lld[4];
#pragma unroll
    for (int m = 0; m < 4; m++) {
        int i = t + 256 * m;
        lld[m] = lam[(size_t)b * Kk * Vv + i] + conv_b[i >> 6];
    }

    // ---- write phase ----
    {
        int i = t;
        if (i < 368) *(reinterpret_cast<uint4*>(gsT) + i) = gld0;
        int i2 = t + 256;
        if (i2 < 368) *(reinterpret_cast<uint4*>(gsT) + i2) = gld1;
    }
    {
        int i = t;
        int np = i >> 4, seg = i & 15;
        *reinterpret_cast<uint2*>(&qsT[np][seg * 4]) = qld0;
        int i2 = t + 256;
        int np2 = i2 >> 4, seg2 = i2 & 15;
        *reinterpret_cast<uint2*>(&qsT[np2][seg2 * 4]) = qld1;
    }
    {
        int i = t;
        int j = i >> 3, seg = i & 7;
        *reinterpret_cast<uint4*>(&vvsT[j][seg * 8]) = vld0;
        int i2 = t + 256;
        if (i2 < 432) {
            int j2 = i2 >> 3, seg2 = i2 & 7;
            *reinterpret_cast<uint4*>(&vvsT[j2][seg2 * 8]) = vld1;
        }
    }
#pragma unroll
    for (int m = 0; m < 4; m++) {
        int i = t + 256 * m;
        lcs[i >> 6][i & 63] = lld[m];
    }
    __syncthreads();

    // ---- main ----
    int np = t & 31;
    int vgp = t >> 5;

    float acc[4][8];
#pragma unroll
    for (int h = 0; h < 4; h++)
#pragma unroll
        for (int vl = 0; vl < 8; vl++) acc[h][vl] = 0.f;

#pragma unroll
    for (int r = 0; r < Rr; r++) {
        ushort4 g4 = *reinterpret_cast<const ushort4*>(&gsT[r][np][0]);
        uint4 w4 = *reinterpret_cast<const uint4*>(&vvsT[np + r][vgp * 8]);
        float gh[4] = {bf2f(g4.x), bf2f(g4.y), bf2f(g4.z), bf2f(g4.w)};
        float wv[8];
        wv[0] = bflo(w4.x); wv[1] = bfhi(w4.x);
        wv[2] = bflo(w4.y); wv[3] = bfhi(w4.y);
        wv[4] = bflo(w4.z); wv[5] = bfhi(w4.z);
        wv[6] = bflo(w4.w); wv[7] = bfhi(w4.w);
#pragma unroll
        for (int h = 0; h < 4; h++)
#pragma unroll
            for (int vl = 0; vl < 8; vl++) acc[h][vl] += gh[h] * wv[vl];
    }

#pragma unroll
    for (int k = 0; k < 16; k++) {
        ushort4 q4 = *reinterpret_cast<const ushort4*>(&qsT[np][k * 4]);
        float qh[4] = {bf2f(q4.x), bf2f(q4.y), bf2f(q4.z), bf2f(q4.w)};
        const float4* lr = reinterpret_cast<const float4*>(&lcs[k][vgp * 8]);
        float4 la = lr[0], lb = lr[1];
        float lv[8] = {la.x, la.y, la.z, la.w, lb.x, lb.y, lb.z, lb.w};
#pragma unroll
        for (int h = 0; h < 4; h++)
#pragma unroll
            for (int vl = 0; vl < 8; vl++) acc[h][vl] += qh[h] * lv[vl];
    }

    float* ob = out + (size_t)b * 256 * Nn + n0 + np;
#pragma unroll
    for (int h = 0; h < 4; h++)
#pragma unroll
        for (int vl = 0; vl < 8; vl++)
            ob[(size_t)(h * 64 + vgp * 8 + vl) * Nn] = acc[h][vl];
}

extern "C" void kernel_launch(void* const* d_in, const int* in_sizes, int n_in,
                              void* d_out, int out_size, void* d_ws, size_t ws_size,
                              hipStream_t stream) {
    const float* x      = (const float*)d_in[0];
    const float* Wq     = (const float*)d_in[1];
    const float* qg     = (const float*)d_in[2];
    const float* qb     = (const float*)d_in[3];
    const float* qm     = (const float*)d_in[4];
    const float* qv     = (const float*)d_in[5];
    const float* Wk     = (const float*)d_in[6];
    const float* Wv     = (const float*)d_in[7];
    const float* vg     = (const float*)d_in[8];
    const float* vb     = (const float*)d_in[9];
    const float* vm     = (const float*)d_in[10];
    const float* vvar   = (const float*)d_in[11];
    const float* conv_w = (const float*)d_in[12];
    const float* conv_b = (const float*)d_in[13];
    float* out = (float*)d_out;

    float* wsf = (float*)d_ws;
    ushort* Wf16  = (ushort*)wsf;                       // 36864 u16 = 18432 f
    float*  bias  = wsf + 18432;                        // 256 f
    float*  kbuf  = wsf + 18688;                        // 16*16*4096 = 1048576 f
    float*  lam   = wsf + 1067264;                      // 16384 f
    ushort* qbufT = (ushort*)(wsf + 1083648);           // 16*4096*64 u16 = 2097152 f
    ushort* vbufT = (ushort*)(wsf + 3180800);           // 16*4096*64 u16 = 2097152 f
    ushort* gbuf  = (ushort*)(wsf + 5277952);           // 16*23*4096*4 u16 = 3014656 f

    pack_kernel<<<Cc, 256, 0, stream>>>(Wq, qg, qb, qm, qv, Wk, Wv, vg, vb, vm, vvar,
                                        Wf16, bias);
    proj_mfma_kernel<<<dim3(Nn / 64, Bn), 256, 0, stream>>>(x, Wf16, bias,
                                                            qbufT, kbuf, vbufT);
    g_kernel<<<dim3(Nn / 256, Bn), 256, 0, stream>>>(qbufT, conv_w, gbuf);
    softmax_kernel<<<dim3(Kk, Bn), 256, 0, stream>>>(kbuf);
    hipMemsetAsync(lam, 0, (size_t)Bn * Kk * Vv * sizeof(float), stream);
    lamc_kernel<<<dim3(Nn / NCHUNK, Bn), 256, 0, stream>>>(kbuf, vbufT, lam);
    fused_out_kernel<<<dim3(Nn / TN, Bn), 256, 0, stream>>>(qbufT, vbufT, gbuf, lam,
                                                            conv_b, out);
}

// Round 15
// 74.894 us; speedup vs baseline: 1.3619x; 1.0020x over previous
//
#include <hip/hip_runtime.h>
#include <hip/hip_bf16.h>

typedef unsigned int uint;
typedef unsigned short ushort;

// Dims
#define Bn 16
#define Dd 256
#define Nn 4096
#define Hh 4
#define Kk 16
#define Vv 64
#define Rr 23
#define Cc 144   // 64 q + 16 k + 64 v
#define NRT 9    // 144/16 row-tiles

typedef short bf16x8s __attribute__((ext_vector_type(8)));
typedef float f32x4 __attribute__((ext_vector_type(4)));
typedef float f32x2v __attribute__((ext_vector_type(2)));

static __device__ __forceinline__ ushort f2bf(float f) {
    __hip_bfloat16 h = __float2bfloat16(f);
    return __builtin_bit_cast(ushort, h);
}
static __device__ __forceinline__ float bf2f(ushort u) {
    return __uint_as_float(((uint)u) << 16);
}
static __device__ __forceinline__ float bflo(uint u) { return __uint_as_float(u << 16); }
static __device__ __forceinline__ float bfhi(uint u) { return __uint_as_float(u & 0xffff0000u); }

// ---------------- Kernel 1: pack 144 BN-folded rows (bf16, A-fragment order) ----------------
__global__ __launch_bounds__(256) void pack_kernel(
    const float* __restrict__ Wq, const float* __restrict__ qg, const float* __restrict__ qb,
    const float* __restrict__ qm, const float* __restrict__ qv,
    const float* __restrict__ Wk, const float* __restrict__ Wv,
    const float* __restrict__ vg, const float* __restrict__ vb,
    const float* __restrict__ vm, const float* __restrict__ vvar,
    ushort* __restrict__ Wf16, float* __restrict__ bias) {
    int c = blockIdx.x;       // 0..143
    int d = threadIdx.x;      // 0..255
    float scale, bs;
    const float* src;
    if (c < 64) {
        scale = qg[c] * rsqrtf(qv[c] + 1e-5f);
        bs = qb[c] - qm[c] * scale;
        src = Wq + c * Dd;
    } else if (c < 80) {
        scale = 1.f; bs = 0.f;
        src = Wk + (c - 64) * Dd;
    } else {
        int j = c - 80;
        scale = vg[j] * rsqrtf(vvar[j] + 1e-5f);
        bs = vb[j] - vm[j] * scale;
        src = Wv + j * Dd;
    }
    int rt = c >> 4, lm = c & 15;
    int kk = d >> 5, hi = (d >> 3) & 3, j = d & 7;
    Wf16[((rt * 8 + kk) * 64 + hi * 16 + lm) * 8 + j] = f2bf(src[d] * scale);
    if (d == 0) bias[c] = bs;
}

// ---------------- Kernel 2: MFMA projection -> consumer-layout buffers (R14 version) ---------
__global__ __launch_bounds__(256, 4) void proj_mfma_kernel(
    const float* __restrict__ x, const ushort* __restrict__ Wf16,
    const float* __restrict__ bias,
    ushort* __restrict__ qbufT, float* __restrict__ kbuf,
    ushort* __restrict__ vbufT) {
    __shared__ ushort Wlds[NRT * 2 * 64 * 8];   // 18432 B (2 k-steps per phase)

    int b = blockIdx.y;
    int n0 = blockIdx.x * 64;
    int t = threadIdx.x;
    int w = t >> 6, l = t & 63;
    int lm = l & 15, hi = l >> 4;
    int n = n0 + w * 16 + lm;     // this lane's output column

    const uint* WfU = (const uint*)Wf16;
    uint* WldsU = (uint*)Wlds;

    f32x4 acc[NRT];
#pragma unroll
    for (int rt = 0; rt < NRT; rt++) acc[rt] = (f32x4){0.f, 0.f, 0.f, 0.f};

    const float* xb = x + (size_t)b * Dd * Nn + n;

#pragma unroll
    for (int p = 0; p < 4; p++) {
        int kb = p * 2;
        if (p) __syncthreads();
#pragma unroll
        for (int i = 0; i < 18; i++) {
            int flat = t + 256 * i;
            int f2 = flat >> 8;          // rt*2 + kkl
            int rt = f2 >> 1, kkl = f2 & 1;
            WldsU[flat] = WfU[((rt * 8 + kb + kkl) << 8) + (flat & 255)];
        }
        __syncthreads();

#pragma unroll
        for (int kkl = 0; kkl < 2; kkl++) {
            int kk = kb + kkl;
            const float* xp = xb + (size_t)(kk * 32 + hi * 8) * Nn;
            float f[8];
#pragma unroll
            for (int j = 0; j < 8; j++) f[j] = xp[(size_t)j * Nn];
            bf16x8s bfrag;
#pragma unroll
            for (int j = 0; j < 8; j++) bfrag[j] = (short)f2bf(f[j]);
#pragma unroll
            for (int rt = 0; rt < NRT; rt++) {
                bf16x8s afrag = *reinterpret_cast<const bf16x8s*>(
                    &Wlds[(size_t)((rt * 2 + kkl) * 64 + l) * 8]);
                acc[rt] = __builtin_amdgcn_mfma_f32_16x16x32_bf16(afrag, bfrag, acc[rt], 0, 0, 0);
            }
        }
    }

    // ---- epilogue ----
#pragma unroll
    for (int rr = 0; rr < 4; rr++) {
        int kc = hi * 4 + rr;
        kbuf[((size_t)b * 16 + kc) * Nn + n] = acc[4][rr] + bias[64 + kc];
    }

    __syncthreads();   // done reading Wlds; reuse as transpose buffer (exactly 18432 B)
    {
        int nl = w * 16 + lm;
#pragma unroll
        for (int rt = 0; rt < 4; rt++)
#pragma unroll
            for (int rr = 0; rr < 4; rr++) {
                int kq = hi * 4 + rr;
                Wlds[nl * 72 + kq * 4 + rt] = f2bf(acc[rt][rr] + bias[rt * 16 + kq]);
            }
#pragma unroll
        for (int rt = 5; rt < 9; rt++)
#pragma unroll
            for (int rr = 0; rr < 4; rr++) {
                int v = (rt - 5) * 16 + hi * 4 + rr;
                Wlds[4608 + nl * 72 + v] = f2bf(acc[rt][rr] + bias[80 + v]);
            }
    }
    __syncthreads();

#pragma unroll
    for (int m = 0; m < 2; m++) {
        int i = t + 256 * m;
        int row = i >> 3, seg = i & 7;
        uint4 u = *reinterpret_cast<const uint4*>(&Wlds[row * 72 + seg * 8]);
        *reinterpret_cast<uint4*>(&qbufT[((size_t)b * Nn + n0 + row) * 64 + seg * 8]) = u;
    }
#pragma unroll
    for (int m = 0; m < 2; m++) {
        int i = t + 256 * m;
        int row = i >> 3, seg = i & 7;
        uint4 u = *reinterpret_cast<const uint4*>(&Wlds[4608 + row * 72 + seg * 8]);
        *reinterpret_cast<uint4*>(&vbufT[((size_t)b * Nn + n0 + row) * 64 + seg * 8]) = u;
    }
}

// ---------------- Kernel 2b: g_kernel — gbuf[b][r][n][h] = sum_k q[k][h] * cw[k][r] ---------
__global__ __launch_bounds__(256) void g_kernel(
    const ushort* __restrict__ qbufT, const float* __restrict__ conv_w,
    ushort* __restrict__ gbuf) {
    __shared__ float cws[Kk][24];   // [k][r], padded
    int b = blockIdx.y;
    int n = blockIdx.x * 256 + threadIdx.x;
    int t = threadIdx.x;
    for (int i = t; i < Kk * Rr; i += 256) cws[i / Rr][i % Rr] = conv_w[i];
    __syncthreads();

    float qf[16][4];
    const uint4* qp = reinterpret_cast<const uint4*>(&qbufT[((size_t)b * Nn + n) * 64]);
#pragma unroll
    for (int m = 0; m < 8; m++) {
        uint4 u = qp[m];
        uint vals[4] = {u.x, u.y, u.z, u.w};
#pragma unroll
        for (int j = 0; j < 4; j++) {
            int idx = m * 8 + j * 2;        // = k*4 + h, h even
            int k = idx >> 2, h = idx & 3;
            qf[k][h]     = bflo(vals[j]);
            qf[k][h + 1] = bfhi(vals[j]);
        }
    }

#pragma unroll
    for (int r = 0; r < Rr; r++) {
        float g0 = 0.f, g1 = 0.f, g2 = 0.f, g3 = 0.f;
#pragma unroll
        for (int k = 0; k < 16; k++) {
            float c = cws[k][r];
            g0 += qf[k][0] * c;
            g1 += qf[k][1] * c;
            g2 += qf[k][2] * c;
            g3 += qf[k][3] * c;
        }
        uint2 o;
        o.x = ((uint)f2bf(g1) << 16) | (uint)f2bf(g0);
        o.y = ((uint)f2bf(g3) << 16) | (uint)f2bf(g2);
        *reinterpret_cast<uint2*>(&gbuf[(((size_t)b * Rr + r) * Nn + n) * 4]) = o;
    }
}

// ---------------- Kernel 3: softmax over n for k channels (kbuf) ----------------
__global__ __launch_bounds__(256) void softmax_kernel(float* __restrict__ kbuf) {
    int b = blockIdx.y, kc = blockIdx.x;
    float* row = kbuf + ((size_t)b * 16 + kc) * Nn;
    int t = threadIdx.x;
    float vals[16];
    float m = -1e30f;
#pragma unroll
    for (int i = 0; i < 16; i++) {
        vals[i] = row[t + 256 * i];
        m = fmaxf(m, vals[i]);
    }
#pragma unroll
    for (int off = 32; off; off >>= 1) m = fmaxf(m, __shfl_xor(m, off));
    __shared__ float sm[4], ss[4];
    int wave = t >> 6;
    if ((t & 63) == 0) sm[wave] = m;
    __syncthreads();
    m = fmaxf(fmaxf(sm[0], sm[1]), fmaxf(sm[2], sm[3]));
    float s = 0.f;
#pragma unroll
    for (int i = 0; i < 16; i++) {
        vals[i] = __expf(vals[i] - m);
        s += vals[i];
    }
#pragma unroll
    for (int off = 32; off; off >>= 1) s += __shfl_xor(s, off);
    if ((t & 63) == 0) ss[wave] = s;
    __syncthreads();
    s = ss[0] + ss[1] + ss[2] + ss[3];
    float inv = 1.f / s;
#pragma unroll
    for (int i = 0; i < 16; i++) row[t + 256 * i] = vals[i] * inv;
}

// ---------------- Kernel 4: lam_c[b][16][64] = sum_n kk*vv ----------------
#define NCHUNK 128
__global__ __launch_bounds__(256) void lamc_kernel(
    const float* __restrict__ kbuf, const ushort* __restrict__ vbufT,
    float* __restrict__ lam) {
    int b = blockIdx.y;
    int n0 = blockIdx.x * NCHUNK;
    __shared__ float kks[Kk][NCHUNK + 1];   // 8256 B
    __shared__ ushort vvT[NCHUNK][72];      // 18432 B, rows 144 B
    int t = threadIdx.x;
#pragma unroll
    for (int m = 0; m < 2; m++) {
        int i = t + 256 * m;
        int r = i >> 5, seg = i & 31;
        float4 f = *reinterpret_cast<const float4*>(&kbuf[((size_t)b * 16 + r) * Nn + n0 + seg * 4]);
        kks[r][seg * 4 + 0] = f.x;
        kks[r][seg * 4 + 1] = f.y;
        kks[r][seg * 4 + 2] = f.z;
        kks[r][seg * 4 + 3] = f.w;
    }
#pragma unroll
    for (int m = 0; m < 4; m++) {
        int i = t + 256 * m;
        int row = i >> 3, seg = i & 7;
        uint4 u = *reinterpret_cast<const uint4*>(&vbufT[((size_t)b * Nn + n0 + row) * 64 + seg * 8]);
        *reinterpret_cast<uint4*>(&vvT[row][seg * 8]) = u;
    }
    __syncthreads();
    int v = t & 63, k0 = t >> 6;
    float acc4[4] = {0.f, 0.f, 0.f, 0.f};
    for (int nl = 0; nl < NCHUNK; nl++) {
        float wv = bf2f(vvT[nl][v]);
#pragma unroll
        for (int j2 = 0; j2 < 4; j2++) acc4[j2] += kks[k0 + 4 * j2][nl] * wv;
    }
#pragma unroll
    for (int j2 = 0; j2 < 4; j2++)
        atomicAdd(&lam[((size_t)b * Kk + k0 + 4 * j2) * Vv + v], acc4[j2]);
}

// ---------------- Kernel 5: fused position-lambda + apply (packed fp32 math) ----------------
// TN=32, 256 threads = (vgp 0..7)x(np 0..31). acc as f32x2 pairs over v -> v_pk_fma_f32.
#define TN 32
__global__ __launch_bounds__(256, 7) void fused_out_kernel(
    const ushort* __restrict__ qbufT, const ushort* __restrict__ vbufT,
    const ushort* __restrict__ gbuf, const float* __restrict__ lam,
    const float* __restrict__ conv_b, float* __restrict__ out) {
    __shared__ ushort vvsT[54][72];       // [j][v] bf16; n = n0-11+j; rows 144 B
    __shared__ ushort qsT[TN][68];        // [np][k*4+h] bf16; rows 136 B
    __shared__ ushort gsT[Rr][TN][4];     // [r][np][h] bf16 (linear copy of gbuf chunk)
    __shared__ float  lcs[Kk][Vv];        // lam_c + conv_b

    int b = blockIdx.y;
    int n0 = blockIdx.x * TN;
    int t = threadIdx.x;

    // ---- load phase (all globals issued before any LDS write) ----
    uint4 gld0, gld1;
    {
        int i = t;
        int r = i >> 4, seg = i & 15;
        if (i < 368)
            gld0 = *reinterpret_cast<const uint4*>(&gbuf[(((size_t)b * Rr + r) * Nn + n0) * 4 + seg * 8]);
        int i2 = t + 256;
        int r2 = i2 >> 4, seg2 = i2 & 15;
        if (i2 < 368)
            gld1 = *reinterpret_cast<const uint4*>(&gbuf[(((size_t)b * Rr + r2) * Nn + n0) * 4 + seg2 * 8]);
    }
    uint2 qld0, qld1;
    {
        int i = t;
        int np = i >> 4, seg = i & 15;
        qld0 = *reinterpret_cast<const uint2*>(&qbufT[((size_t)b * Nn + n0 + np) * 64 + seg * 4]);
        int i2 = t + 256;
        int np2 = i2 >> 4, seg2 = i2 & 15;
        qld1 = *reinterpret_cast<const uint2*>(&qbufT[((size_t)b * Nn + n0 + np2) * 64 + seg2 * 4]);
    }
    uint4 vld0 = {0, 0, 0, 0}, vld1 = {0, 0, 0, 0};
    {
        int i = t;
        int j = i >> 3, seg = i & 7;
        int nn = n0 - 11 + j;
        if (nn >= 0 && nn < Nn)
            vld0 = *reinterpret_cast<const uint4*>(&vbufT[((size_t)b * Nn + nn) * 64 + seg * 8]);
        int i2 = t + 256;
        int j2 = i2 >> 3, seg2 = i2 & 7;
        int nn2 = n0 - 11 + j2;
        if (i2 < 432 && nn2 >= 0 && nn2 < Nn)
            vld1 = *reinterpret_cast<const uint4*>(&vbufT[((size_t)b * Nn + nn2) * 64 + seg2 * 8]);
    }
    float lld[4];
#pragma unroll
    for (int m = 0; m < 4; m++) {
        int i = t + 256 * m;
        lld[m] = lam[(size_t)b * Kk * Vv + i] + conv_b[i >> 6];
    }

    // ---- write phase ----
    {
        int i = t;
        if (i < 368) *(reinterpret_cast<uint4*>(gsT) + i) = gld0;
        int i2 = t + 256;
        if (i2 < 368) *(reinterpret_cast<uint4*>(gsT) + i2) = gld1;
    }
    {
        int i = t;
        int np = i >> 4, seg = i & 15;
        *reinterpret_cast<uint2*>(&qsT[np][seg * 4]) = qld0;
        int i2 = t + 256;
        int np2 = i2 >> 4, seg2 = i2 & 15;
        *reinterpret_cast<uint2*>(&qsT[np2][seg2 * 4]) = qld1;
    }
    {
        int i = t;
        int j = i >> 3, seg = i & 7;
        *reinterpret_cast<uint4*>(&vvsT[j][seg * 8]) = vld0;
        int i2 = t + 256;
        if (i2 < 432) {
            int j2 = i2 >> 3, seg2 = i2 & 7;
            *reinterpret_cast<uint4*>(&vvsT[j2][seg2 * 8]) = vld1;
        }
    }
#pragma unroll
    for (int m = 0; m < 4; m++) {
        int i = t + 256 * m;
        lcs[i >> 6][i & 63] = lld[m];
    }
    __syncthreads();

    // ---- main ----
    int np = t & 31;
    int vgp = t >> 5;

    f32x2v acc2[4][4];    // [h][v-pair]; pair (2vp, 2vp+1) within vgp's 8 v
#pragma unroll
    for (int h = 0; h < 4; h++)
#pragma unroll
        for (int vp = 0; vp < 4; vp++) acc2[h][vp] = (f32x2v){0.f, 0.f};

    // position: per r, 1 b64 (g: 4 h) + 1 b128 (vv: 8 v), 16 pk-FMA
#pragma unroll
    for (int r = 0; r < Rr; r++) {
        ushort4 g4 = *reinterpret_cast<const ushort4*>(&gsT[r][np][0]);
        uint4 w4 = *reinterpret_cast<const uint4*>(&vvsT[np + r][vgp * 8]);
        float gh[4] = {bf2f(g4.x), bf2f(g4.y), bf2f(g4.z), bf2f(g4.w)};
        f32x2v wv2[4];
        wv2[0] = (f32x2v){bflo(w4.x), bfhi(w4.x)};
        wv2[1] = (f32x2v){bflo(w4.y), bfhi(w4.y)};
        wv2[2] = (f32x2v){bflo(w4.z), bfhi(w4.z)};
        wv2[3] = (f32x2v){bflo(w4.w), bfhi(w4.w)};
#pragma unroll
        for (int h = 0; h < 4; h++) {
            f32x2v gb = (f32x2v){gh[h], gh[h]};
#pragma unroll
            for (int vp = 0; vp < 4; vp++) acc2[h][vp] += gb * wv2[vp];
        }
    }

    // content: per k, 1 b64 (q: 4 h) + 2 broadcast b128 (lc), 16 pk-FMA
#pragma unroll
    for (int k = 0; k < 16; k++) {
        ushort4 q4 = *reinterpret_cast<const ushort4*>(&qsT[np][k * 4]);
        float qh[4] = {bf2f(q4.x), bf2f(q4.y), bf2f(q4.z), bf2f(q4.w)};
        const float4* lr = reinterpret_cast<const float4*>(&lcs[k][vgp * 8]);
        float4 la = lr[0], lb = lr[1];
        f32x2v lv2[4] = {(f32x2v){la.x, la.y}, (f32x2v){la.z, la.w},
                         (f32x2v){lb.x, lb.y}, (f32x2v){lb.z, lb.w}};
#pragma unroll
        for (int h = 0; h < 4; h++) {
            f32x2v qb = (f32x2v){qh[h], qh[h]};
#pragma unroll
            for (int vp = 0; vp < 4; vp++) acc2[h][vp] += qb * lv2[vp];
        }
    }

    // store: 32 coalesced b32 stores (pairs are different output rows -> scalar)
    float* ob = out + (size_t)b * 256 * Nn + n0 + np;
#pragma unroll
    for (int h = 0; h < 4; h++)
#pragma unroll
        for (int vp = 0; vp < 4; vp++) {
            ob[(size_t)(h * 64 + vgp * 8 + 2 * vp + 0) * Nn] = acc2[h][vp][0];
            ob[(size_t)(h * 64 + vgp * 8 + 2 * vp + 1) * Nn] = acc2[h][vp][1];
        }
}

extern "C" void kernel_launch(void* const* d_in, const int* in_sizes, int n_in,
                              void* d_out, int out_size, void* d_ws, size_t ws_size,
                              hipStream_t stream) {
    const float* x      = (const float*)d_in[0];
    const float* Wq     = (const float*)d_in[1];
    const float* qg     = (const float*)d_in[2];
    const float* qb     = (const float*)d_in[3];
    const float* qm     = (const float*)d_in[4];
    const float* qv     = (const float*)d_in[5];
    const float* Wk     = (const float*)d_in[6];
    const float* Wv     = (const float*)d_in[7];
    const float* vg     = (const float*)d_in[8];
    const float* vb     = (const float*)d_in[9];
    const float* vm     = (const float*)d_in[10];
    const float* vvar   = (const float*)d_in[11];
    const float* conv_w = (const float*)d_in[12];
    const float* conv_b = (const float*)d_in[13];
    float* out = (float*)d_out;

    float* wsf = (float*)d_ws;
    ushort* Wf16  = (ushort*)wsf;                       // 36864 u16 = 18432 f
    float*  bias  = wsf + 18432;                        // 256 f
    float*  kbuf  = wsf + 18688;                        // 16*16*4096 = 1048576 f
    float*  lam   = wsf + 1067264;                      // 16384 f
    ushort* qbufT = (ushort*)(wsf + 1083648);           // 16*4096*64 u16 = 2097152 f
    ushort* vbufT = (ushort*)(wsf + 3180800);           // 16*4096*64 u16 = 2097152 f
    ushort* gbuf  = (ushort*)(wsf + 5277952);           // 16*23*4096*4 u16 = 3014656 f

    pack_kernel<<<Cc, 256, 0, stream>>>(Wq, qg, qb, qm, qv, Wk, Wv, vg, vb, vm, vvar,
                                        Wf16, bias);
    proj_mfma_kernel<<<dim3(Nn / 64, Bn), 256, 0, stream>>>(x, Wf16, bias,
                                                            qbufT, kbuf, vbufT);
    g_kernel<<<dim3(Nn / 256, Bn), 256, 0, stream>>>(qbufT, conv_w, gbuf);
    softmax_kernel<<<dim3(Kk, Bn), 256, 0, stream>>>(kbuf);
    hipMemsetAsync(lam, 0, (size_t)Bn * Kk * Vv * sizeof(float), stream);
    lamc_kernel<<<dim3(Nn / NCHUNK, Bn), 256, 0, stream>>>(kbuf, vbufT, lam);
    fused_out_kernel<<<dim3(Nn / TN, Bn), 256, 0, stream>>>(qbufT, vbufT, gbuf, lam,
                                                            conv_b, out);
}